// Round 1
// baseline (199.354 us; speedup 1.0000x reference)
//
#include <hip/hip_runtime.h>
#include <hip/hip_bf16.h>

// GCN 2-layer encoder. R15: L2-resident gather planes.
//  - g is written as 4 planes of [N][32] bf16 (3.2MB each < 4MB per-XCD L2);
//    g2 as 2 planes of [N][32] (SPLIT=1 gemm).
//  - New gather kernels: 1 block = 64 nodes, slots + per-source dinv staged
//    into LDS ONCE (stride-49 padded -> conflict-free ds_read_b64 broadcast),
//    then the planes are looped INSIDE the block. Grid = ceil(N/64) = 782
//    blocks, all resident -> lockstep plane progression -> one plane hot per
//    XCD L2 at a time.
// Otherwise identical to R14: block-specialized mega-kernel (binA || gemm1),
// bucketed u16 CSR build, MFMA GEMMs.
// out[d] = dinv[d] * sum_{s in N(d) U {d}} dinv[s]*h[s] + b,  h = in @ W1

constexpr int FIN = 128;
constexpr int HID = 128;
constexpr int FOUT = 64;
constexpr int CAP = 48;     // adjacency slots per node
constexpr int NPB = 98;     // nodes per bucket
constexpr int BCAP = 3072;  // pairs per bucket region
constexpr int OVF_MAX = 65536;

typedef __attribute__((ext_vector_type(8))) short s16x8;
typedef __attribute__((ext_vector_type(4))) float f32x4;

static __device__ __forceinline__ float bf2f(__hip_bfloat16 v) { return __bfloat162float(v); }
static __device__ __forceinline__ float lo2f(unsigned u) { union { unsigned i; float f; } c; c.i = u << 16; return c.f; }
static __device__ __forceinline__ float hi2f(unsigned u) { union { unsigned i; float f; } c; c.i = u & 0xffff0000u; return c.f; }
static __device__ __forceinline__ unsigned short f2bfu(float f) {
    __hip_bfloat16 h = __float2bfloat16(f);
    union { __hip_bfloat16 h; unsigned short u; } c; c.h = h; return c.u;
}
static __device__ __forceinline__ unsigned pack2(float a, float b) {
    return (unsigned)f2bfu(a) | ((unsigned)f2bfu(b) << 16);
}
static __device__ __forceinline__ void acc_add(float* acc, uint4 v) {
    acc[0] += lo2f(v.x); acc[1] += hi2f(v.x);
    acc[2] += lo2f(v.y); acc[3] += hi2f(v.y);
    acc[4] += lo2f(v.z); acc[5] += hi2f(v.z);
    acc[6] += lo2f(v.w); acc[7] += hi2f(v.w);
}
static __device__ __forceinline__ void acc_fma(float* acc, uint4 v, float w) {
    acc[0] += w * lo2f(v.x); acc[1] += w * hi2f(v.x);
    acc[2] += w * lo2f(v.y); acc[3] += w * hi2f(v.y);
    acc[4] += w * lo2f(v.z); acc[5] += w * hi2f(v.z);
    acc[6] += w * lo2f(v.w); acc[7] += w * hi2f(v.w);
}

struct SW { int s; float w; };

// flags detect + zero gcur/ovf counters. zero_cnt!=0 (fallback path): zero cnt.
__global__ __launch_bounds__(256) void k_detect(const unsigned* __restrict__ xw,
                                                const int* __restrict__ eiw,
                                                int E, int* __restrict__ flags,
                                                int* __restrict__ gcur,
                                                int* __restrict__ cnt, int N, int zero_cnt) {
    if (zero_cnt)
        for (long i = (long)blockIdx.x * 256 + threadIdx.x; i < N; i += (long)gridDim.x * 256)
            cnt[i] = 0;
    if (blockIdx.x != 0) return;
    for (int i = threadIdx.x; i < 514; i += 256) gcur[i] = 0;
    __shared__ int s_bf16like, s_oddnz;
    if (threadIdx.x == 0) { s_bf16like = 0; s_oddnz = 0; }
    __syncthreads();
    int c = 0;
    for (int i = threadIdx.x; i < 4096; i += 256) {
        unsigned ex = ((xw[i] & 0xffffu) >> 7) & 0xffu;
        if (ex >= 117u && ex <= 130u) c++;
    }
    atomicAdd(&s_bf16like, c);
    int nz = 0;
    for (int i = threadIdx.x; i < 2048; i += 256)
        if (eiw[2 * i + 1] != 0) nz++;
    atomicAdd(&s_oddnz, nz);
    __syncthreads();
    if (threadIdx.x == 0) {
        flags[0] = (s_bf16like < 2048) ? 1 : 0;
        flags[1] = (s_oddnz == 0) ? 1 : 0;
    }
}

// Mega kernel: blocks [0,GB) = gemm1 (unscaled, 4 column planes of 32);
//              blocks [GB,GB+AB) = binA edge partition. Dynamic LDS.
__global__ __launch_bounds__(256) void k_mega(const void* __restrict__ Xp,
                                              const void* __restrict__ Wp,
                                              const int* __restrict__ ei, int E, int N,
                                              int nbuk, int GB,
                                              int* __restrict__ gcur,
                                              unsigned* __restrict__ pairs,
                                              int2* __restrict__ ovfA,
                                              int* __restrict__ ovfAcnt,
                                              __hip_bfloat16* __restrict__ G,
                                              const int* __restrict__ flags) {
    extern __shared__ __align__(16) char smem[];
    const int tid = threadIdx.x;
    if ((int)blockIdx.x < GB) {
        // ---------------- GEMM1: g = X @ W1 (unscaled), 4 column planes ----
        short* Wt = (short*)smem;                    // 128x136 bf16 = 34816 B
        const bool f32m = flags[0] != 0;
        for (int i = tid; i < 128 * 128; i += 256) {
            int k = i >> 7, n = i & 127;
            float wv = f32m ? ((const float*)Wp)[(long)k * 128 + n]
                            : bf2f(((const __hip_bfloat16*)Wp)[(long)k * 128 + n]);
            Wt[n * 136 + k] = (short)f2bfu(wv);
        }
        __syncthreads();
        const int w = tid >> 6, lane = tid & 63;
        const int m = lane & 15, quad = lane >> 4;
        const int rowA = blockIdx.x * 64 + w * 16 + m;
        const int rowc = rowA < N ? rowA : N - 1;
        s16x8 afr[4];
#pragma unroll
        for (int kc = 0; kc < 4; ++kc) {
            const int k0 = kc * 32 + quad * 8;
            if (!f32m) {
                afr[kc] = *(const s16x8*)((const __hip_bfloat16*)Xp + (long)rowc * 128 + k0);
            } else {
                const float* p = (const float*)Xp + (long)rowc * 128 + k0;
                s16x8 t;
#pragma unroll
                for (int j = 0; j < 8; ++j) t[j] = (short)f2bfu(p[j]);
                afr[kc] = t;
            }
        }
        const int rbase = blockIdx.x * 64 + w * 16 + quad * 4;
#pragma unroll
        for (int ct = 0; ct < 8; ++ct) {
            f32x4 acc = {0.f, 0.f, 0.f, 0.f};
#pragma unroll
            for (int kc = 0; kc < 4; ++kc) {
                s16x8 bfr = *(const s16x8*)&Wt[(ct * 16 + m) * 136 + kc * 32 + quad * 8];
                acc = __builtin_amdgcn_mfma_f32_16x16x32_bf16(afr[kc], bfr, acc, 0, 0, 0);
            }
            const int plane = ct >> 1;                 // 4 planes of 32 cols
            const int cp = (ct & 1) * 16 + m;
#pragma unroll
            for (int r = 0; r < 4; ++r) {
                int rr = rbase + r;
                if (rr < N)
                    G[(long)plane * N * 32 + (long)rr * 32 + cp] = __float2bfloat16(acc[r]);
            }
        }
    } else {
        // ---------------- binA: edge partition into buckets ----------------
        int* hist = (int*)smem;          // 512 ints
        int* gbase = hist + 512;         // 512 ints
        const long base = (long)(blockIdx.x - GB) * 2048;
        const bool i64 = flags[1] != 0;
        int se[8], de[8];
        for (int b = tid; b < nbuk; b += 256) hist[b] = 0;
        __syncthreads();
#pragma unroll
        for (int j = 0; j < 8; ++j) {
            long i = base + j * 256 + tid;
            int s = 0, d = -1;
            if (i < E) {
                if (i64) { s = ((const int2*)ei)[i].x; d = ((const int2*)(ei + 2 * (long)E))[i].x; }
                else     { s = ei[i]; d = ei[(long)E + i]; }
                if ((unsigned)s >= (unsigned)N || (unsigned)d >= (unsigned)N) d = -1;
            }
            se[j] = s; de[j] = d;
            if (d >= 0) atomicAdd(&hist[d / NPB], 1);
        }
        __syncthreads();
        for (int b = tid; b < nbuk; b += 256) {
            int h = hist[b];
            gbase[b] = h > 0 ? atomicAdd(&gcur[b], h) : 0;
            hist[b] = 0;
        }
        __syncthreads();
#pragma unroll
        for (int j = 0; j < 8; ++j) {
            int d = de[j];
            if (d < 0) continue;
            int b = d / NPB;
            int p = gbase[b] + atomicAdd(&hist[b], 1);
            if (p < BCAP) {
                pairs[(long)b * BCAP + p] = ((unsigned)(d - b * NPB) << 16) | (unsigned)se[j];
            } else {
                int op = atomicAdd(ovfAcnt, 1);
                if (op < OVF_MAX) ovfA[op] = make_int2(d, se[j]);
            }
        }
    }
}

// Phase B: per bucket, build cnt+slots+dinv in LDS (incl. phase-A ovf fold).
__global__ __launch_bounds__(256) void k_binB(const int* __restrict__ gcur,
                                              const unsigned* __restrict__ pairs,
                                              const int2* __restrict__ ovfA,
                                              const int* __restrict__ ovfAcnt,
                                              int* __restrict__ cnt,
                                              float* __restrict__ dinv,
                                              unsigned short* __restrict__ slots,
                                              int2* __restrict__ ovf2,
                                              int* __restrict__ ovf2cnt, int N) {
    __shared__ int cntL[NPB];
    __shared__ __align__(16) unsigned short slotsL[NPB * CAP];
    const int b = blockIdx.x;
    const int tid = threadIdx.x;
    const int d0 = b * NPB;
    const int nd = min(NPB, N - d0);
    if (nd <= 0) return;
    for (int i = tid; i < NPB; i += 256) cntL[i] = 0;
    __syncthreads();
    const int c = min(gcur[b], BCAP);
    const unsigned* pb = pairs + (long)b * BCAP;
    for (int i = tid; i < c; i += 256) {
        unsigned p = pb[i];
        int ld = p >> 16;
        int pos = atomicAdd(&cntL[ld], 1);
        if (pos < CAP) {
            slotsL[ld * CAP + pos] = (unsigned short)(p & 0xffffu);
        } else {
            int op = atomicAdd(ovf2cnt, 1);
            if (op < OVF_MAX) ovf2[op] = make_int2(d0 + ld, (int)(p & 0xffffu));
        }
    }
    int na = *ovfAcnt; na = na < OVF_MAX ? na : OVF_MAX;
    for (int i = tid; i < na; i += 256) {
        int2 p = ovfA[i];
        int ld = p.x - d0;
        if ((unsigned)ld < (unsigned)nd) {
            int pos = atomicAdd(&cntL[ld], 1);
            if (pos < CAP) {
                slotsL[ld * CAP + pos] = (unsigned short)p.y;
            } else {
                int op = atomicAdd(ovf2cnt, 1);
                if (op < OVF_MAX) ovf2[op] = p;
            }
        }
    }
    __syncthreads();
    for (int i = tid; i < nd; i += 256) {
        cnt[d0 + i] = cntL[i];
        dinv[d0 + i] = rsqrtf((float)(cntL[i] + 1));
    }
    const uint4* sv = (const uint4*)slotsL;
    uint4* gv = (uint4*)(slots + (long)d0 * CAP);
    const int total8 = (nd * CAP) >> 3;
    for (int i = tid; i < total8; i += 256) gv[i] = sv[i];
}

// Fallback direct build for N > 65536 (int slots). cnt must be pre-zeroed.
__global__ __launch_bounds__(256) void k_build_direct(const int* __restrict__ ei, int E, int N,
                                                      int* __restrict__ cnt,
                                                      int* __restrict__ slots,
                                                      int2* __restrict__ ovf2,
                                                      int* __restrict__ ovf2cnt,
                                                      const int* __restrict__ flags) {
    long i = (long)blockIdx.x * 256 + threadIdx.x;
    if (i >= E) return;
    int s, d;
    if (flags[1]) { s = ((const int2*)ei)[i].x; d = ((const int2*)(ei + 2 * (long)E))[i].x; }
    else          { s = ei[i]; d = ei[(long)E + i]; }
    if ((unsigned)s >= (unsigned)N || (unsigned)d >= (unsigned)N) return;
    int pos = atomicAdd(&cnt[d], 1);
    if (pos < CAP) {
        slots[(long)d * CAP + pos] = s;
    } else {
        int op = atomicAdd(ovf2cnt, 1);
        if (op < OVF_MAX) ovf2[op] = make_int2(d, s);
    }
}

// Scaled MFMA GEMM (runs after binB): G = bf16( rsqrt(cnt+1) * (X @ W) ).
// SPLIT=1 writes 2 planes of [N][C/2].
template<int CT, int SPLIT>
__global__ __launch_bounds__(256) void k_gemm(const void* __restrict__ Xp, int x_follows_flag,
                                              const void* __restrict__ Wp,
                                              const int* __restrict__ cnt,
                                              __hip_bfloat16* __restrict__ G,
                                              const int* __restrict__ flags, int N) {
    constexpr int C = CT * 16;
    __shared__ __align__(16) short Wt[C * 136];
    const bool f32m = flags[0] != 0;
    const bool xf32 = (x_follows_flag != 0) && f32m;
    const int tid = threadIdx.x;
    for (int i = tid; i < 128 * C; i += 256) {
        int k = i / C, n = i % C;
        float wv = f32m ? ((const float*)Wp)[(long)k * C + n]
                        : bf2f(((const __hip_bfloat16*)Wp)[(long)k * C + n]);
        Wt[n * 136 + k] = (short)f2bfu(wv);
    }
    __syncthreads();
    const int w = tid >> 6, lane = tid & 63;
    const int m = lane & 15, quad = lane >> 4;
    const int rowA = blockIdx.x * 64 + w * 16 + m;
    const int rowc = rowA < N ? rowA : N - 1;
    s16x8 afr[4];
#pragma unroll
    for (int kc = 0; kc < 4; ++kc) {
        const int k0 = kc * 32 + quad * 8;
        if (!xf32) {
            afr[kc] = *(const s16x8*)((const __hip_bfloat16*)Xp + (long)rowc * 128 + k0);
        } else {
            const float* p = (const float*)Xp + (long)rowc * 128 + k0;
            s16x8 t;
#pragma unroll
            for (int j = 0; j < 8; ++j) t[j] = (short)f2bfu(p[j]);
            afr[kc] = t;
        }
    }
    const int rbase = blockIdx.x * 64 + w * 16 + quad * 4;
    float dv[4];
#pragma unroll
    for (int r = 0; r < 4; ++r) {
        int rr = min(rbase + r, N - 1);
        dv[r] = rsqrtf((float)(cnt[rr] + 1));
    }
#pragma unroll
    for (int ct = 0; ct < CT; ++ct) {
        f32x4 acc = {0.f, 0.f, 0.f, 0.f};
#pragma unroll
        for (int kc = 0; kc < 4; ++kc) {
            s16x8 bfr = *(const s16x8*)&Wt[(ct * 16 + m) * 136 + kc * 32 + quad * 8];
            acc = __builtin_amdgcn_mfma_f32_16x16x32_bf16(afr[kc], bfr, acc, 0, 0, 0);
        }
#pragma unroll
        for (int r = 0; r < 4; ++r) {
            int rr = rbase + r;
            if (rr < N) {
                long off;
                if (SPLIT) {
                    const int plane = ct / (CT / 2);
                    const int cp = (ct % (CT / 2)) * 16 + m;
                    off = (long)plane * N * (C / 2) + (long)rr * (C / 2) + cp;
                } else {
                    off = (long)rr * C + ct * 16 + m;
                }
                G[off] = __float2bfloat16(dv[r] * acc[r]);
            }
        }
    }
}

// R15 gather, layer 1: block owns 64 nodes; slots + per-source dinv staged to
// LDS once (stride-49 pad -> conflict-free b64 broadcast); 4 planes of [N][32]
// looped in-block (3.2MB each, L2-resident; all 782 blocks resident ->
// lockstep plane progression). g UNscaled; dinv[s] applied per source.
__global__ __launch_bounds__(256) void k_gather1p(const __hip_bfloat16* __restrict__ G,
                                                  const int* __restrict__ cnt,
                                                  const float* __restrict__ dinv,
                                                  const unsigned short* __restrict__ slots,
                                                  const int2* __restrict__ ovf2,
                                                  const int* __restrict__ ovf2cnt,
                                                  const void* __restrict__ b1,
                                                  __hip_bfloat16* __restrict__ h1,
                                                  const int* __restrict__ flags, int N) {
    __shared__ int cntL[64];
    __shared__ float wsL[64];
    __shared__ __align__(16) SW swL[64 * 49];     // 25088 B, pad 48->49 (banks)
    const int tid = threadIdx.x;
    const int n0 = blockIdx.x * 64;
    const int nd = min(64, N - n0);
    for (int i = tid; i < nd; i += 256) {
        cntL[i] = cnt[n0 + i];
        wsL[i] = dinv[n0 + i];
    }
    __syncthreads();
    for (int j = tid; j < 64 * CAP; j += 256) {
        const int ni = j / CAP, sl = j - ni * CAP;
        if (ni < nd) {
            const int mm = min(cntL[ni], CAP);
            if (sl < mm) {
                const int s = slots[(long)(n0 + ni) * CAP + sl];
                swL[ni * 49 + sl].s = s;
                swL[ni * 49 + sl].w = dinv[s];
            }
        }
    }
    __syncthreads();
    const int grp = tid >> 2, lane = tid & 3;
    if (grp >= nd) return;                        // all barriers done
    const int node = n0 + grp;
    const int cd = cntL[grp];
    const int m = cd < CAP ? cd : CAP;
    const float wself = wsL[grp];
    const SW* sw = &swL[grp * 49];
    const bool f32m = flags[0] != 0;
    for (int P = 0; P < 4; ++P) {
        const __hip_bfloat16* Gp = G + (long)P * N * 32;
        float acc[8] = {0, 0, 0, 0, 0, 0, 0, 0};
        acc_fma(acc, ((const uint4*)(Gp + (long)node * 32))[lane], wself);   // self
        int i = 0;
        for (; i + 7 < m; i += 8) {
            SW a0 = sw[i], a1 = sw[i + 1], a2 = sw[i + 2], a3 = sw[i + 3];
            SW a4 = sw[i + 4], a5 = sw[i + 5], a6 = sw[i + 6], a7 = sw[i + 7];
            uint4 v0 = ((const uint4*)(Gp + (long)a0.s * 32))[lane];
            uint4 v1 = ((const uint4*)(Gp + (long)a1.s * 32))[lane];
            uint4 v2 = ((const uint4*)(Gp + (long)a2.s * 32))[lane];
            uint4 v3 = ((const uint4*)(Gp + (long)a3.s * 32))[lane];
            uint4 v4 = ((const uint4*)(Gp + (long)a4.s * 32))[lane];
            uint4 v5 = ((const uint4*)(Gp + (long)a5.s * 32))[lane];
            uint4 v6 = ((const uint4*)(Gp + (long)a6.s * 32))[lane];
            uint4 v7 = ((const uint4*)(Gp + (long)a7.s * 32))[lane];
            acc_fma(acc, v0, a0.w); acc_fma(acc, v1, a1.w);
            acc_fma(acc, v2, a2.w); acc_fma(acc, v3, a3.w);
            acc_fma(acc, v4, a4.w); acc_fma(acc, v5, a5.w);
            acc_fma(acc, v6, a6.w); acc_fma(acc, v7, a7.w);
        }
        for (; i + 3 < m; i += 4) {
            SW a0 = sw[i], a1 = sw[i + 1], a2 = sw[i + 2], a3 = sw[i + 3];
            uint4 v0 = ((const uint4*)(Gp + (long)a0.s * 32))[lane];
            uint4 v1 = ((const uint4*)(Gp + (long)a1.s * 32))[lane];
            uint4 v2 = ((const uint4*)(Gp + (long)a2.s * 32))[lane];
            uint4 v3 = ((const uint4*)(Gp + (long)a3.s * 32))[lane];
            acc_fma(acc, v0, a0.w); acc_fma(acc, v1, a1.w);
            acc_fma(acc, v2, a2.w); acc_fma(acc, v3, a3.w);
        }
        for (; i < m; ++i) {
            SW a = sw[i];
            acc_fma(acc, ((const uint4*)(Gp + (long)a.s * 32))[lane], a.w);
        }
        if (cd > CAP) {
            int oc = *ovf2cnt; oc = oc < OVF_MAX ? oc : OVF_MAX;
            for (int j = 0; j < oc; ++j)
                if (ovf2[j].x == node) {
                    int s0 = ovf2[j].y;
                    acc_fma(acc, ((const uint4*)(Gp + (long)s0 * 32))[lane], dinv[s0]);
                }
        }
        const int c0 = P * 32 + lane * 8;
        float bv[8];
        if (f32m) {
            const float4* bp = (const float4*)((const float*)b1 + c0);
            float4 b0 = bp[0], b1v = bp[1];
            bv[0] = b0.x; bv[1] = b0.y; bv[2] = b0.z; bv[3] = b0.w;
            bv[4] = b1v.x; bv[5] = b1v.y; bv[6] = b1v.z; bv[7] = b1v.w;
        } else {
            uint4 b = *(const uint4*)((const __hip_bfloat16*)b1 + c0);
            bv[0] = lo2f(b.x); bv[1] = hi2f(b.x); bv[2] = lo2f(b.y); bv[3] = hi2f(b.y);
            bv[4] = lo2f(b.z); bv[5] = hi2f(b.z); bv[6] = lo2f(b.w); bv[7] = hi2f(b.w);
        }
        float o[8];
#pragma unroll
        for (int c = 0; c < 8; ++c) {
            float v = wself * acc[c] + bv[c];
            o[c] = v > 0.f ? v : 0.f;
        }
        uint4 pv = { pack2(o[0], o[1]), pack2(o[2], o[3]), pack2(o[4], o[5]), pack2(o[6], o[7]) };
        ((uint4*)(h1 + (long)node * 128 + P * 32))[lane] = pv;
    }
}

// R15 gather, layer 2: same structure over pre-scaled g2, 2 planes of [N][32].
__global__ __launch_bounds__(256) void k_gather2p(const __hip_bfloat16* __restrict__ G,
                                                  const int* __restrict__ cnt,
                                                  const float* __restrict__ dinv,
                                                  const unsigned short* __restrict__ slots,
                                                  const int2* __restrict__ ovf2,
                                                  const int* __restrict__ ovf2cnt,
                                                  const void* __restrict__ bias,
                                                  void* __restrict__ outp,
                                                  const int* __restrict__ flags, int N) {
    __shared__ int cntL[64];
    __shared__ float wsL[64];
    __shared__ int slL[64 * 49];                   // 12544 B, stride-49 pad
    const int tid = threadIdx.x;
    const int n0 = blockIdx.x * 64;
    const int nd = min(64, N - n0);
    for (int i = tid; i < nd; i += 256) {
        cntL[i] = cnt[n0 + i];
        wsL[i] = dinv[n0 + i];
    }
    __syncthreads();
    for (int j = tid; j < 64 * CAP; j += 256) {
        const int ni = j / CAP, sl = j - ni * CAP;
        if (ni < nd) {
            const int mm = min(cntL[ni], CAP);
            if (sl < mm) slL[ni * 49 + sl] = slots[(long)(n0 + ni) * CAP + sl];
        }
    }
    __syncthreads();
    const int grp = tid >> 2, lane = tid & 3;
    if (grp >= nd) return;
    const int node = n0 + grp;
    const int cd = cntL[grp];
    const int m = cd < CAP ? cd : CAP;
    const float wself = wsL[grp];
    const int* sl = &slL[grp * 49];
    const bool f32m = flags[0] != 0;
    for (int P = 0; P < 2; ++P) {
        const __hip_bfloat16* Gp = G + (long)P * N * 32;
        float acc[8] = {0, 0, 0, 0, 0, 0, 0, 0};
        acc_add(acc, ((const uint4*)(Gp + (long)node * 32))[lane]);          // self
        int i = 0;
        for (; i + 7 < m; i += 8) {
            int s0 = sl[i], s1 = sl[i + 1], s2 = sl[i + 2], s3 = sl[i + 3];
            int s4 = sl[i + 4], s5 = sl[i + 5], s6 = sl[i + 6], s7 = sl[i + 7];
            uint4 v0 = ((const uint4*)(Gp + (long)s0 * 32))[lane];
            uint4 v1 = ((const uint4*)(Gp + (long)s1 * 32))[lane];
            uint4 v2 = ((const uint4*)(Gp + (long)s2 * 32))[lane];
            uint4 v3 = ((const uint4*)(Gp + (long)s3 * 32))[lane];
            uint4 v4 = ((const uint4*)(Gp + (long)s4 * 32))[lane];
            uint4 v5 = ((const uint4*)(Gp + (long)s5 * 32))[lane];
            uint4 v6 = ((const uint4*)(Gp + (long)s6 * 32))[lane];
            uint4 v7 = ((const uint4*)(Gp + (long)s7 * 32))[lane];
            acc_add(acc, v0); acc_add(acc, v1); acc_add(acc, v2); acc_add(acc, v3);
            acc_add(acc, v4); acc_add(acc, v5); acc_add(acc, v6); acc_add(acc, v7);
        }
        for (; i + 3 < m; i += 4) {
            int s0 = sl[i], s1 = sl[i + 1], s2 = sl[i + 2], s3 = sl[i + 3];
            uint4 v0 = ((const uint4*)(Gp + (long)s0 * 32))[lane];
            uint4 v1 = ((const uint4*)(Gp + (long)s1 * 32))[lane];
            uint4 v2 = ((const uint4*)(Gp + (long)s2 * 32))[lane];
            uint4 v3 = ((const uint4*)(Gp + (long)s3 * 32))[lane];
            acc_add(acc, v0); acc_add(acc, v1); acc_add(acc, v2); acc_add(acc, v3);
        }
        for (; i < m; ++i)
            acc_add(acc, ((const uint4*)(Gp + (long)sl[i] * 32))[lane]);
        if (cd > CAP) {
            int oc = *ovf2cnt; oc = oc < OVF_MAX ? oc : OVF_MAX;
            for (int j = 0; j < oc; ++j)
                if (ovf2[j].x == node)
                    acc_add(acc, ((const uint4*)(Gp + (long)ovf2[j].y * 32))[lane]);
        }
        const int c0 = P * 32 + lane * 8;
        float bv[8];
        if (f32m) {
            const float4* bp = (const float4*)((const float*)bias + c0);
            float4 b0 = bp[0], b1 = bp[1];
            bv[0] = b0.x; bv[1] = b0.y; bv[2] = b0.z; bv[3] = b0.w;
            bv[4] = b1.x; bv[5] = b1.y; bv[6] = b1.z; bv[7] = b1.w;
        } else {
            uint4 b = *(const uint4*)((const __hip_bfloat16*)bias + c0);
            bv[0] = lo2f(b.x); bv[1] = hi2f(b.x); bv[2] = lo2f(b.y); bv[3] = hi2f(b.y);
            bv[4] = lo2f(b.z); bv[5] = hi2f(b.z); bv[6] = lo2f(b.w); bv[7] = hi2f(b.w);
        }
        float o[8];
#pragma unroll
        for (int c = 0; c < 8; ++c) o[c] = wself * acc[c] + bv[c];
        if (!f32m) {
            uint4 pv = { pack2(o[0], o[1]), pack2(o[2], o[3]), pack2(o[4], o[5]), pack2(o[6], o[7]) };
            ((uint4*)outp)[(long)node * 8 + P * 4 + lane] = pv;
        } else {
            float4* op = (float4*)((float*)outp + (long)node * FOUT + c0);
            op[0] = make_float4(o[0], o[1], o[2], o[3]);
            op[1] = make_float4(o[4], o[5], o[6], o[7]);
        }
    }
}

// Full-row gather over pre-scaled G (fallback path only).
template<int F, int LAYER1, typename ST>
__global__ __launch_bounds__(256) void k_gather(const __hip_bfloat16* __restrict__ G,
                                                const int* __restrict__ cnt,
                                                const ST* __restrict__ slots,
                                                const int2* __restrict__ ovf2,
                                                const int* __restrict__ ovf2cnt,
                                                const void* __restrict__ bias,
                                                void* __restrict__ outp,
                                                const int* __restrict__ flags, int N) {
    constexpr int L = F / 8;
    constexpr int NODES = 256 / L;
    const int tid = threadIdx.x;
    const int grp = tid / L, lane = tid % L;
    const int node = blockIdx.x * NODES + grp;
    if (node >= N) return;
    const int cd = cnt[node];
    const float wself = rsqrtf((float)(cd + 1));
    const int m = cd < CAP ? cd : CAP;
    const ST* sl = slots + (long)node * CAP;
    float acc[8] = {0, 0, 0, 0, 0, 0, 0, 0};
    acc_add(acc, ((const uint4*)(G + (long)node * F))[lane]);
    int i = 0;
    for (; i + 7 < m; i += 8) {
        int s0 = sl[i], s1 = sl[i + 1], s2 = sl[i + 2], s3 = sl[i + 3];
        int s4 = sl[i + 4], s5 = sl[i + 5], s6 = sl[i + 6], s7 = sl[i + 7];
        uint4 v0 = ((const uint4*)(G + (long)s0 * F))[lane];
        uint4 v1 = ((const uint4*)(G + (long)s1 * F))[lane];
        uint4 v2 = ((const uint4*)(G + (long)s2 * F))[lane];
        uint4 v3 = ((const uint4*)(G + (long)s3 * F))[lane];
        uint4 v4 = ((const uint4*)(G + (long)s4 * F))[lane];
        uint4 v5 = ((const uint4*)(G + (long)s5 * F))[lane];
        uint4 v6 = ((const uint4*)(G + (long)s6 * F))[lane];
        uint4 v7 = ((const uint4*)(G + (long)s7 * F))[lane];
        acc_add(acc, v0); acc_add(acc, v1); acc_add(acc, v2); acc_add(acc, v3);
        acc_add(acc, v4); acc_add(acc, v5); acc_add(acc, v6); acc_add(acc, v7);
    }
    for (; i + 3 < m; i += 4) {
        int s0 = sl[i], s1 = sl[i + 1], s2 = sl[i + 2], s3 = sl[i + 3];
        uint4 v0 = ((const uint4*)(G + (long)s0 * F))[lane];
        uint4 v1 = ((const uint4*)(G + (long)s1 * F))[lane];
        uint4 v2 = ((const uint4*)(G + (long)s2 * F))[lane];
        uint4 v3 = ((const uint4*)(G + (long)s3 * F))[lane];
        acc_add(acc, v0); acc_add(acc, v1); acc_add(acc, v2); acc_add(acc, v3);
    }
    for (; i < m; ++i)
        acc_add(acc, ((const uint4*)(G + (long)sl[i] * F))[lane]);
    if (cd > CAP) {
        int oc = *ovf2cnt; oc = oc < OVF_MAX ? oc : OVF_MAX;
        for (int j = 0; j < oc; ++j)
            if (ovf2[j].x == node)
                acc_add(acc, ((const uint4*)(G + (long)ovf2[j].y * F))[lane]);
    }
    const bool f32m = flags[0] != 0;
    const int c0 = lane * 8;
    float bv[8];
    if (f32m) {
        const float4* bp = (const float4*)((const float*)bias + c0);
        float4 b0 = bp[0], b1 = bp[1];
        bv[0] = b0.x; bv[1] = b0.y; bv[2] = b0.z; bv[3] = b0.w;
        bv[4] = b1.x; bv[5] = b1.y; bv[6] = b1.z; bv[7] = b1.w;
    } else {
        uint4 b = *(const uint4*)((const __hip_bfloat16*)bias + c0);
        bv[0] = lo2f(b.x); bv[1] = hi2f(b.x); bv[2] = lo2f(b.y); bv[3] = hi2f(b.y);
        bv[4] = lo2f(b.z); bv[5] = hi2f(b.z); bv[6] = lo2f(b.w); bv[7] = hi2f(b.w);
    }
    float o[8];
#pragma unroll
    for (int c = 0; c < 8; ++c) {
        float v = wself * acc[c] + bv[c];
        o[c] = (LAYER1 && v < 0.f) ? 0.f : v;
    }
    if (LAYER1 || !f32m) {
        uint4 pv = { pack2(o[0], o[1]), pack2(o[2], o[3]), pack2(o[4], o[5]), pack2(o[6], o[7]) };
        ((uint4*)outp)[(long)node * L + lane] = pv;
    } else {
        float4* op = (float4*)((float*)outp + (long)node * F + c0);
        op[0] = make_float4(o[0], o[1], o[2], o[3]);
        op[1] = make_float4(o[4], o[5], o[6], o[7]);
    }
}

extern "C" void kernel_launch(void* const* d_in, const int* in_sizes, int n_in,
                              void* d_out, int out_size, void* d_ws, size_t ws_size,
                              hipStream_t stream) {
    const void* x  = d_in[0];
    const int*  ei = (const int*)d_in[1];
    const void* W1 = d_in[2];
    const void* b1 = d_in[3];
    const void* W2 = d_in[4];
    const void* b2 = d_in[5];

    const int N = in_sizes[0] / FIN;   // 50000
    const int E = in_sizes[1] / 2;     // 800000
    const int nbuk = (N + NPB - 1) / NPB;   // 511 (<=512 for u16 path)

    // ws layout (bytes), peak ~37.3MB:
    //   flags @0; gcur @4096 (512+2 ints)
    //   cnt @65536 (4N); dinv @266240 (4N)
    //   ovfA @524288; ovf2 @1048576
    //   slots @2097152 (u16 4.8MB / int 9.6MB)
    //   g @11730944 (12.8MB; 4 planes of N*32 / fallback [N][128]; g2 overlays)
    //   pairs @24530944 (6.28MB; h1 overlays after binB)
    char* ws = (char*)d_ws;
    int*   flags   = (int*)ws;
    int*   gcur    = (int*)(ws + 4096);
    int*   ovfAcnt = gcur + 512;
    int*   ovf2cnt = gcur + 513;
    int*   cnt     = (int*)(ws + 65536);
    float* dinv    = (float*)(ws + 266240);
    int2*  ovfA    = (int2*)(ws + 524288);
    int2*  ovf2    = (int2*)(ws + 1048576);
    unsigned short* slots16 = (unsigned short*)(ws + 2097152);
    int*   slots32 = (int*)(ws + 2097152);
    __hip_bfloat16* g  = (__hip_bfloat16*)(ws + 11730944);
    __hip_bfloat16* g2 = g;
    unsigned* pairs = (unsigned*)(ws + 24530944);
    __hip_bfloat16* h1 = (__hip_bfloat16*)(ws + 24530944);

    const int GB = (N + 63) / 64;
    const int AB = (E + 2047) / 2048;
    const int EB = (E + 255) / 256;

    if (N <= 65536 && nbuk <= 512) {
        k_detect<<<1, 256, 0, stream>>>((const unsigned*)x, ei, E, flags, gcur, cnt, N, 0);
        k_mega<<<GB + AB, 256, 34816, stream>>>(x, W1, ei, E, N, nbuk, GB,
                                                gcur, pairs, ovfA, ovfAcnt, g, flags);
        k_binB<<<nbuk, 256, 0, stream>>>(gcur, pairs, ovfA, ovfAcnt, cnt, dinv, slots16, ovf2, ovf2cnt, N);
        const int GBL = (N + 63) / 64;
        k_gather1p<<<GBL, 256, 0, stream>>>(g, cnt, dinv, slots16, ovf2, ovf2cnt, b1, h1, flags, N);
        k_gemm<4, 1><<<GB, 256, 0, stream>>>(h1, 0, W2, cnt, g2, flags, N);
        k_gather2p<<<GBL, 256, 0, stream>>>(g2, cnt, dinv, slots16, ovf2, ovf2cnt, b2, d_out, flags, N);
    } else {
        k_detect<<<64, 256, 0, stream>>>((const unsigned*)x, ei, E, flags, gcur, cnt, N, 1);
        k_build_direct<<<EB, 256, 0, stream>>>(ei, E, N, cnt, slots32, ovf2, ovf2cnt, flags);
        k_gemm<8, 0><<<GB, 256, 0, stream>>>(x, 1, W1, cnt, g, flags, N);
        k_gather<128, 1, int><<<(N + 15) / 16, 256, 0, stream>>>(
            g, cnt, slots32, ovf2, ovf2cnt, b1, h1, flags, N);
        k_gemm<4, 0><<<GB, 256, 0, stream>>>(h1, 0, W2, cnt, g2, flags, N);
        k_gather<64, 0, int><<<(N + 31) / 32, 256, 0, stream>>>(
            g2, cnt, slots32, ovf2, ovf2cnt, b2, d_out, flags, N);
    }
}

// Round 2
// 190.896 us; speedup vs baseline: 1.0443x; 1.0443x over previous
//
#include <hip/hip_runtime.h>
#include <hip/hip_bf16.h>

// GCN 2-layer encoder. R16: R14 gather geometry restored (2 planes of [N][64],
// 8-lane groups = 128B per random source row), with R15's only-free parts kept:
// gather1 loops both planes INSIDE one block (grid 3126->1563) and stages
// slots + per-source dinv into LDS once (stride-49 pad). Layer-2 gather and
// GEMMs identical to R14. binA/binB unchanged.
// out[d] = dinv[d] * sum_{s in N(d) U {d}} dinv[s]*h[s] + b,  h = in @ W1

constexpr int FIN = 128;
constexpr int HID = 128;
constexpr int FOUT = 64;
constexpr int CAP = 48;     // adjacency slots per node
constexpr int NPB = 98;     // nodes per bucket
constexpr int BCAP = 3072;  // pairs per bucket region
constexpr int OVF_MAX = 65536;

typedef __attribute__((ext_vector_type(8))) short s16x8;
typedef __attribute__((ext_vector_type(4))) float f32x4;

static __device__ __forceinline__ float bf2f(__hip_bfloat16 v) { return __bfloat162float(v); }
static __device__ __forceinline__ float lo2f(unsigned u) { union { unsigned i; float f; } c; c.i = u << 16; return c.f; }
static __device__ __forceinline__ float hi2f(unsigned u) { union { unsigned i; float f; } c; c.i = u & 0xffff0000u; return c.f; }
static __device__ __forceinline__ unsigned short f2bfu(float f) {
    __hip_bfloat16 h = __float2bfloat16(f);
    union { __hip_bfloat16 h; unsigned short u; } c; c.h = h; return c.u;
}
static __device__ __forceinline__ unsigned pack2(float a, float b) {
    return (unsigned)f2bfu(a) | ((unsigned)f2bfu(b) << 16);
}
static __device__ __forceinline__ void acc_add(float* acc, uint4 v) {
    acc[0] += lo2f(v.x); acc[1] += hi2f(v.x);
    acc[2] += lo2f(v.y); acc[3] += hi2f(v.y);
    acc[4] += lo2f(v.z); acc[5] += hi2f(v.z);
    acc[6] += lo2f(v.w); acc[7] += hi2f(v.w);
}
static __device__ __forceinline__ void acc_fma(float* acc, uint4 v, float w) {
    acc[0] += w * lo2f(v.x); acc[1] += w * hi2f(v.x);
    acc[2] += w * lo2f(v.y); acc[3] += w * hi2f(v.y);
    acc[4] += w * lo2f(v.z); acc[5] += w * hi2f(v.z);
    acc[6] += w * lo2f(v.w); acc[7] += w * hi2f(v.w);
}

struct SW { int s; float w; };

// flags detect + zero gcur/ovf counters. zero_cnt!=0 (fallback path): zero cnt.
__global__ __launch_bounds__(256) void k_detect(const unsigned* __restrict__ xw,
                                                const int* __restrict__ eiw,
                                                int E, int* __restrict__ flags,
                                                int* __restrict__ gcur,
                                                int* __restrict__ cnt, int N, int zero_cnt) {
    if (zero_cnt)
        for (long i = (long)blockIdx.x * 256 + threadIdx.x; i < N; i += (long)gridDim.x * 256)
            cnt[i] = 0;
    if (blockIdx.x != 0) return;
    for (int i = threadIdx.x; i < 514; i += 256) gcur[i] = 0;
    __shared__ int s_bf16like, s_oddnz;
    if (threadIdx.x == 0) { s_bf16like = 0; s_oddnz = 0; }
    __syncthreads();
    int c = 0;
    for (int i = threadIdx.x; i < 4096; i += 256) {
        unsigned ex = ((xw[i] & 0xffffu) >> 7) & 0xffu;
        if (ex >= 117u && ex <= 130u) c++;
    }
    atomicAdd(&s_bf16like, c);
    int nz = 0;
    for (int i = threadIdx.x; i < 2048; i += 256)
        if (eiw[2 * i + 1] != 0) nz++;
    atomicAdd(&s_oddnz, nz);
    __syncthreads();
    if (threadIdx.x == 0) {
        flags[0] = (s_bf16like < 2048) ? 1 : 0;
        flags[1] = (s_oddnz == 0) ? 1 : 0;
    }
}

// Mega kernel: blocks [0,GB) = gemm1 (unscaled, 2 column planes of 64);
//              blocks [GB,GB+AB) = binA edge partition. Dynamic LDS.
__global__ __launch_bounds__(256) void k_mega(const void* __restrict__ Xp,
                                              const void* __restrict__ Wp,
                                              const int* __restrict__ ei, int E, int N,
                                              int nbuk, int GB,
                                              int* __restrict__ gcur,
                                              unsigned* __restrict__ pairs,
                                              int2* __restrict__ ovfA,
                                              int* __restrict__ ovfAcnt,
                                              __hip_bfloat16* __restrict__ G,
                                              const int* __restrict__ flags) {
    extern __shared__ __align__(16) char smem[];
    const int tid = threadIdx.x;
    if ((int)blockIdx.x < GB) {
        // ---------------- GEMM1: g = X @ W1 (unscaled), 2 column planes ----
        short* Wt = (short*)smem;                    // 128x136 bf16 = 34816 B
        const bool f32m = flags[0] != 0;
        for (int i = tid; i < 128 * 128; i += 256) {
            int k = i >> 7, n = i & 127;
            float wv = f32m ? ((const float*)Wp)[(long)k * 128 + n]
                            : bf2f(((const __hip_bfloat16*)Wp)[(long)k * 128 + n]);
            Wt[n * 136 + k] = (short)f2bfu(wv);
        }
        __syncthreads();
        const int w = tid >> 6, lane = tid & 63;
        const int m = lane & 15, quad = lane >> 4;
        const int rowA = blockIdx.x * 64 + w * 16 + m;
        const int rowc = rowA < N ? rowA : N - 1;
        s16x8 afr[4];
#pragma unroll
        for (int kc = 0; kc < 4; ++kc) {
            const int k0 = kc * 32 + quad * 8;
            if (!f32m) {
                afr[kc] = *(const s16x8*)((const __hip_bfloat16*)Xp + (long)rowc * 128 + k0);
            } else {
                const float* p = (const float*)Xp + (long)rowc * 128 + k0;
                s16x8 t;
#pragma unroll
                for (int j = 0; j < 8; ++j) t[j] = (short)f2bfu(p[j]);
                afr[kc] = t;
            }
        }
        const int rbase = blockIdx.x * 64 + w * 16 + quad * 4;
#pragma unroll
        for (int ct = 0; ct < 8; ++ct) {
            f32x4 acc = {0.f, 0.f, 0.f, 0.f};
#pragma unroll
            for (int kc = 0; kc < 4; ++kc) {
                s16x8 bfr = *(const s16x8*)&Wt[(ct * 16 + m) * 136 + kc * 32 + quad * 8];
                acc = __builtin_amdgcn_mfma_f32_16x16x32_bf16(afr[kc], bfr, acc, 0, 0, 0);
            }
            const int plane = ct >> 2;                 // 2 planes of 64 cols
            const int cp = (ct & 3) * 16 + m;
#pragma unroll
            for (int r = 0; r < 4; ++r) {
                int rr = rbase + r;
                if (rr < N)
                    G[(long)plane * N * 64 + (long)rr * 64 + cp] = __float2bfloat16(acc[r]);
            }
        }
    } else {
        // ---------------- binA: edge partition into buckets ----------------
        int* hist = (int*)smem;          // 512 ints
        int* gbase = hist + 512;         // 512 ints
        const long base = (long)(blockIdx.x - GB) * 2048;
        const bool i64 = flags[1] != 0;
        int se[8], de[8];
        for (int b = tid; b < nbuk; b += 256) hist[b] = 0;
        __syncthreads();
#pragma unroll
        for (int j = 0; j < 8; ++j) {
            long i = base + j * 256 + tid;
            int s = 0, d = -1;
            if (i < E) {
                if (i64) { s = ((const int2*)ei)[i].x; d = ((const int2*)(ei + 2 * (long)E))[i].x; }
                else     { s = ei[i]; d = ei[(long)E + i]; }
                if ((unsigned)s >= (unsigned)N || (unsigned)d >= (unsigned)N) d = -1;
            }
            se[j] = s; de[j] = d;
            if (d >= 0) atomicAdd(&hist[d / NPB], 1);
        }
        __syncthreads();
        for (int b = tid; b < nbuk; b += 256) {
            int h = hist[b];
            gbase[b] = h > 0 ? atomicAdd(&gcur[b], h) : 0;
            hist[b] = 0;
        }
        __syncthreads();
#pragma unroll
        for (int j = 0; j < 8; ++j) {
            int d = de[j];
            if (d < 0) continue;
            int b = d / NPB;
            int p = gbase[b] + atomicAdd(&hist[b], 1);
            if (p < BCAP) {
                pairs[(long)b * BCAP + p] = ((unsigned)(d - b * NPB) << 16) | (unsigned)se[j];
            } else {
                int op = atomicAdd(ovfAcnt, 1);
                if (op < OVF_MAX) ovfA[op] = make_int2(d, se[j]);
            }
        }
    }
}

// Phase B: per bucket, build cnt+slots+dinv in LDS (incl. phase-A ovf fold).
__global__ __launch_bounds__(256) void k_binB(const int* __restrict__ gcur,
                                              const unsigned* __restrict__ pairs,
                                              const int2* __restrict__ ovfA,
                                              const int* __restrict__ ovfAcnt,
                                              int* __restrict__ cnt,
                                              float* __restrict__ dinv,
                                              unsigned short* __restrict__ slots,
                                              int2* __restrict__ ovf2,
                                              int* __restrict__ ovf2cnt, int N) {
    __shared__ int cntL[NPB];
    __shared__ __align__(16) unsigned short slotsL[NPB * CAP];
    const int b = blockIdx.x;
    const int tid = threadIdx.x;
    const int d0 = b * NPB;
    const int nd = min(NPB, N - d0);
    if (nd <= 0) return;
    for (int i = tid; i < NPB; i += 256) cntL[i] = 0;
    __syncthreads();
    const int c = min(gcur[b], BCAP);
    const unsigned* pb = pairs + (long)b * BCAP;
    for (int i = tid; i < c; i += 256) {
        unsigned p = pb[i];
        int ld = p >> 16;
        int pos = atomicAdd(&cntL[ld], 1);
        if (pos < CAP) {
            slotsL[ld * CAP + pos] = (unsigned short)(p & 0xffffu);
        } else {
            int op = atomicAdd(ovf2cnt, 1);
            if (op < OVF_MAX) ovf2[op] = make_int2(d0 + ld, (int)(p & 0xffffu));
        }
    }
    int na = *ovfAcnt; na = na < OVF_MAX ? na : OVF_MAX;
    for (int i = tid; i < na; i += 256) {
        int2 p = ovfA[i];
        int ld = p.x - d0;
        if ((unsigned)ld < (unsigned)nd) {
            int pos = atomicAdd(&cntL[ld], 1);
            if (pos < CAP) {
                slotsL[ld * CAP + pos] = (unsigned short)p.y;
            } else {
                int op = atomicAdd(ovf2cnt, 1);
                if (op < OVF_MAX) ovf2[op] = p;
            }
        }
    }
    __syncthreads();
    for (int i = tid; i < nd; i += 256) {
        cnt[d0 + i] = cntL[i];
        dinv[d0 + i] = rsqrtf((float)(cntL[i] + 1));
    }
    const uint4* sv = (const uint4*)slotsL;
    uint4* gv = (uint4*)(slots + (long)d0 * CAP);
    const int total8 = (nd * CAP) >> 3;
    for (int i = tid; i < total8; i += 256) gv[i] = sv[i];
}

// Fallback direct build for N > 65536 (int slots). cnt must be pre-zeroed.
__global__ __launch_bounds__(256) void k_build_direct(const int* __restrict__ ei, int E, int N,
                                                      int* __restrict__ cnt,
                                                      int* __restrict__ slots,
                                                      int2* __restrict__ ovf2,
                                                      int* __restrict__ ovf2cnt,
                                                      const int* __restrict__ flags) {
    long i = (long)blockIdx.x * 256 + threadIdx.x;
    if (i >= E) return;
    int s, d;
    if (flags[1]) { s = ((const int2*)ei)[i].x; d = ((const int2*)(ei + 2 * (long)E))[i].x; }
    else          { s = ei[i]; d = ei[(long)E + i]; }
    if ((unsigned)s >= (unsigned)N || (unsigned)d >= (unsigned)N) return;
    int pos = atomicAdd(&cnt[d], 1);
    if (pos < CAP) {
        slots[(long)d * CAP + pos] = s;
    } else {
        int op = atomicAdd(ovf2cnt, 1);
        if (op < OVF_MAX) ovf2[op] = make_int2(d, s);
    }
}

// Scaled MFMA GEMM (runs after binB): G = bf16( rsqrt(cnt+1) * (X @ W) ).
template<int CT, int SPLIT>
__global__ __launch_bounds__(256) void k_gemm(const void* __restrict__ Xp, int x_follows_flag,
                                              const void* __restrict__ Wp,
                                              const int* __restrict__ cnt,
                                              __hip_bfloat16* __restrict__ G,
                                              const int* __restrict__ flags, int N) {
    constexpr int C = CT * 16;
    __shared__ __align__(16) short Wt[C * 136];
    const bool f32m = flags[0] != 0;
    const bool xf32 = (x_follows_flag != 0) && f32m;
    const int tid = threadIdx.x;
    for (int i = tid; i < 128 * C; i += 256) {
        int k = i / C, n = i % C;
        float wv = f32m ? ((const float*)Wp)[(long)k * C + n]
                        : bf2f(((const __hip_bfloat16*)Wp)[(long)k * C + n]);
        Wt[n * 136 + k] = (short)f2bfu(wv);
    }
    __syncthreads();
    const int w = tid >> 6, lane = tid & 63;
    const int m = lane & 15, quad = lane >> 4;
    const int rowA = blockIdx.x * 64 + w * 16 + m;
    const int rowc = rowA < N ? rowA : N - 1;
    s16x8 afr[4];
#pragma unroll
    for (int kc = 0; kc < 4; ++kc) {
        const int k0 = kc * 32 + quad * 8;
        if (!xf32) {
            afr[kc] = *(const s16x8*)((const __hip_bfloat16*)Xp + (long)rowc * 128 + k0);
        } else {
            const float* p = (const float*)Xp + (long)rowc * 128 + k0;
            s16x8 t;
#pragma unroll
            for (int j = 0; j < 8; ++j) t[j] = (short)f2bfu(p[j]);
            afr[kc] = t;
        }
    }
    const int rbase = blockIdx.x * 64 + w * 16 + quad * 4;
    float dv[4];
#pragma unroll
    for (int r = 0; r < 4; ++r) {
        int rr = min(rbase + r, N - 1);
        dv[r] = rsqrtf((float)(cnt[rr] + 1));
    }
#pragma unroll
    for (int ct = 0; ct < CT; ++ct) {
        f32x4 acc = {0.f, 0.f, 0.f, 0.f};
#pragma unroll
        for (int kc = 0; kc < 4; ++kc) {
            s16x8 bfr = *(const s16x8*)&Wt[(ct * 16 + m) * 136 + kc * 32 + quad * 8];
            acc = __builtin_amdgcn_mfma_f32_16x16x32_bf16(afr[kc], bfr, acc, 0, 0, 0);
        }
#pragma unroll
        for (int r = 0; r < 4; ++r) {
            int rr = rbase + r;
            if (rr < N) {
                long off;
                if (SPLIT) {
                    const int plane = ct / (CT / 2);
                    const int cp = (ct % (CT / 2)) * 16 + m;
                    off = (long)plane * N * (C / 2) + (long)rr * (C / 2) + cp;
                } else {
                    off = (long)rr * C + ct * 16 + m;
                }
                G[off] = __float2bfloat16(dv[r] * acc[r]);
            }
        }
    }
}

// R16 gather, layer 1: block owns 32 nodes; slots + per-source dinv staged to
// LDS once (stride-49 pad). 2 planes of [N][64] (128B rows, 8-lane groups as
// R14) looped sequentially in-block; ~all 1563 blocks resident -> blocks pass
// through plane 0 then plane 1 together. g UNscaled; dinv[s] applied per src.
__global__ __launch_bounds__(256) void k_gather1b(const __hip_bfloat16* __restrict__ G,
                                                  const int* __restrict__ cnt,
                                                  const float* __restrict__ dinv,
                                                  const unsigned short* __restrict__ slots,
                                                  const int2* __restrict__ ovf2,
                                                  const int* __restrict__ ovf2cnt,
                                                  const void* __restrict__ b1,
                                                  __hip_bfloat16* __restrict__ h1,
                                                  const int* __restrict__ flags, int N) {
    __shared__ int cntL[32];
    __shared__ float wsL[32];
    __shared__ __align__(16) SW swL[32 * 49];     // 12544 B, pad 48->49
    const int tid = threadIdx.x;
    const int n0 = blockIdx.x * 32;
    const int nd = min(32, N - n0);
    for (int i = tid; i < nd; i += 256) {
        cntL[i] = cnt[n0 + i];
        wsL[i] = dinv[n0 + i];
    }
    __syncthreads();
    for (int j = tid; j < 32 * CAP; j += 256) {
        const int ni = j / CAP, sl = j - ni * CAP;
        if (ni < nd) {
            const int mm = min(cntL[ni], CAP);
            if (sl < mm) {
                const int s = slots[(long)(n0 + ni) * CAP + sl];
                swL[ni * 49 + sl].s = s;
                swL[ni * 49 + sl].w = dinv[s];
            }
        }
    }
    __syncthreads();
    const int grp = tid >> 3, lane = tid & 7;
    if (grp >= nd) return;                        // all barriers done
    const int node = n0 + grp;
    const int cd = cntL[grp];
    const int m = cd < CAP ? cd : CAP;
    const float wself = wsL[grp];
    const SW* sw = &swL[grp * 49];
    const bool f32m = flags[0] != 0;
    for (int P = 0; P < 2; ++P) {
        const __hip_bfloat16* Gp = G + (long)P * N * 64;
        float acc[8] = {0, 0, 0, 0, 0, 0, 0, 0};
        acc_fma(acc, ((const uint4*)(Gp + (long)node * 64))[lane], wself);   // self
        int i = 0;
        for (; i + 7 < m; i += 8) {
            SW a0 = sw[i], a1 = sw[i + 1], a2 = sw[i + 2], a3 = sw[i + 3];
            SW a4 = sw[i + 4], a5 = sw[i + 5], a6 = sw[i + 6], a7 = sw[i + 7];
            uint4 v0 = ((const uint4*)(Gp + (long)a0.s * 64))[lane];
            uint4 v1 = ((const uint4*)(Gp + (long)a1.s * 64))[lane];
            uint4 v2 = ((const uint4*)(Gp + (long)a2.s * 64))[lane];
            uint4 v3 = ((const uint4*)(Gp + (long)a3.s * 64))[lane];
            uint4 v4 = ((const uint4*)(Gp + (long)a4.s * 64))[lane];
            uint4 v5 = ((const uint4*)(Gp + (long)a5.s * 64))[lane];
            uint4 v6 = ((const uint4*)(Gp + (long)a6.s * 64))[lane];
            uint4 v7 = ((const uint4*)(Gp + (long)a7.s * 64))[lane];
            acc_fma(acc, v0, a0.w); acc_fma(acc, v1, a1.w);
            acc_fma(acc, v2, a2.w); acc_fma(acc, v3, a3.w);
            acc_fma(acc, v4, a4.w); acc_fma(acc, v5, a5.w);
            acc_fma(acc, v6, a6.w); acc_fma(acc, v7, a7.w);
        }
        for (; i + 3 < m; i += 4) {
            SW a0 = sw[i], a1 = sw[i + 1], a2 = sw[i + 2], a3 = sw[i + 3];
            uint4 v0 = ((const uint4*)(Gp + (long)a0.s * 64))[lane];
            uint4 v1 = ((const uint4*)(Gp + (long)a1.s * 64))[lane];
            uint4 v2 = ((const uint4*)(Gp + (long)a2.s * 64))[lane];
            uint4 v3 = ((const uint4*)(Gp + (long)a3.s * 64))[lane];
            acc_fma(acc, v0, a0.w); acc_fma(acc, v1, a1.w);
            acc_fma(acc, v2, a2.w); acc_fma(acc, v3, a3.w);
        }
        for (; i < m; ++i) {
            SW a = sw[i];
            acc_fma(acc, ((const uint4*)(Gp + (long)a.s * 64))[lane], a.w);
        }
        if (cd > CAP) {
            int oc = *ovf2cnt; oc = oc < OVF_MAX ? oc : OVF_MAX;
            for (int j = 0; j < oc; ++j)
                if (ovf2[j].x == node) {
                    int s0 = ovf2[j].y;
                    acc_fma(acc, ((const uint4*)(Gp + (long)s0 * 64))[lane], dinv[s0]);
                }
        }
        const int c0 = P * 64 + lane * 8;
        float bv[8];
        if (f32m) {
            const float4* bp = (const float4*)((const float*)b1 + c0);
            float4 b0 = bp[0], b1v = bp[1];
            bv[0] = b0.x; bv[1] = b0.y; bv[2] = b0.z; bv[3] = b0.w;
            bv[4] = b1v.x; bv[5] = b1v.y; bv[6] = b1v.z; bv[7] = b1v.w;
        } else {
            uint4 b = *(const uint4*)((const __hip_bfloat16*)b1 + c0);
            bv[0] = lo2f(b.x); bv[1] = hi2f(b.x); bv[2] = lo2f(b.y); bv[3] = hi2f(b.y);
            bv[4] = lo2f(b.z); bv[5] = hi2f(b.z); bv[6] = lo2f(b.w); bv[7] = hi2f(b.w);
        }
        float o[8];
#pragma unroll
        for (int c = 0; c < 8; ++c) {
            float v = wself * acc[c] + bv[c];
            o[c] = v > 0.f ? v : 0.f;
        }
        uint4 pv = { pack2(o[0], o[1]), pack2(o[2], o[3]), pack2(o[4], o[5]), pack2(o[6], o[7]) };
        ((uint4*)(h1 + (long)node * 128 + P * 64))[lane] = pv;
    }
}

// Full-row gather over pre-scaled G (layer 2 and fallback layer 1).
template<int F, int LAYER1, typename ST>
__global__ __launch_bounds__(256) void k_gather(const __hip_bfloat16* __restrict__ G,
                                                const int* __restrict__ cnt,
                                                const ST* __restrict__ slots,
                                                const int2* __restrict__ ovf2,
                                                const int* __restrict__ ovf2cnt,
                                                const void* __restrict__ bias,
                                                void* __restrict__ outp,
                                                const int* __restrict__ flags, int N) {
    constexpr int L = F / 8;
    constexpr int NODES = 256 / L;
    const int tid = threadIdx.x;
    const int grp = tid / L, lane = tid % L;
    const int node = blockIdx.x * NODES + grp;
    if (node >= N) return;
    const int cd = cnt[node];
    const float wself = rsqrtf((float)(cd + 1));
    const int m = cd < CAP ? cd : CAP;
    const ST* sl = slots + (long)node * CAP;
    float acc[8] = {0, 0, 0, 0, 0, 0, 0, 0};
    acc_add(acc, ((const uint4*)(G + (long)node * F))[lane]);
    int i = 0;
    for (; i + 7 < m; i += 8) {
        int s0 = sl[i], s1 = sl[i + 1], s2 = sl[i + 2], s3 = sl[i + 3];
        int s4 = sl[i + 4], s5 = sl[i + 5], s6 = sl[i + 6], s7 = sl[i + 7];
        uint4 v0 = ((const uint4*)(G + (long)s0 * F))[lane];
        uint4 v1 = ((const uint4*)(G + (long)s1 * F))[lane];
        uint4 v2 = ((const uint4*)(G + (long)s2 * F))[lane];
        uint4 v3 = ((const uint4*)(G + (long)s3 * F))[lane];
        uint4 v4 = ((const uint4*)(G + (long)s4 * F))[lane];
        uint4 v5 = ((const uint4*)(G + (long)s5 * F))[lane];
        uint4 v6 = ((const uint4*)(G + (long)s6 * F))[lane];
        uint4 v7 = ((const uint4*)(G + (long)s7 * F))[lane];
        acc_add(acc, v0); acc_add(acc, v1); acc_add(acc, v2); acc_add(acc, v3);
        acc_add(acc, v4); acc_add(acc, v5); acc_add(acc, v6); acc_add(acc, v7);
    }
    for (; i + 3 < m; i += 4) {
        int s0 = sl[i], s1 = sl[i + 1], s2 = sl[i + 2], s3 = sl[i + 3];
        uint4 v0 = ((const uint4*)(G + (long)s0 * F))[lane];
        uint4 v1 = ((const uint4*)(G + (long)s1 * F))[lane];
        uint4 v2 = ((const uint4*)(G + (long)s2 * F))[lane];
        uint4 v3 = ((const uint4*)(G + (long)s3 * F))[lane];
        acc_add(acc, v0); acc_add(acc, v1); acc_add(acc, v2); acc_add(acc, v3);
    }
    for (; i < m; ++i)
        acc_add(acc, ((const uint4*)(G + (long)sl[i] * F))[lane]);
    if (cd > CAP) {
        int oc = *ovf2cnt; oc = oc < OVF_MAX ? oc : OVF_MAX;
        for (int j = 0; j < oc; ++j)
            if (ovf2[j].x == node)
                acc_add(acc, ((const uint4*)(G + (long)ovf2[j].y * F))[lane]);
    }
    const bool f32m = flags[0] != 0;
    const int c0 = lane * 8;
    float bv[8];
    if (f32m) {
        const float4* bp = (const float4*)((const float*)bias + c0);
        float4 b0 = bp[0], b1 = bp[1];
        bv[0] = b0.x; bv[1] = b0.y; bv[2] = b0.z; bv[3] = b0.w;
        bv[4] = b1.x; bv[5] = b1.y; bv[6] = b1.z; bv[7] = b1.w;
    } else {
        uint4 b = *(const uint4*)((const __hip_bfloat16*)bias + c0);
        bv[0] = lo2f(b.x); bv[1] = hi2f(b.x); bv[2] = lo2f(b.y); bv[3] = hi2f(b.y);
        bv[4] = lo2f(b.z); bv[5] = hi2f(b.z); bv[6] = lo2f(b.w); bv[7] = hi2f(b.w);
    }
    float o[8];
#pragma unroll
    for (int c = 0; c < 8; ++c) {
        float v = wself * acc[c] + bv[c];
        o[c] = (LAYER1 && v < 0.f) ? 0.f : v;
    }
    if (LAYER1 || !f32m) {
        uint4 pv = { pack2(o[0], o[1]), pack2(o[2], o[3]), pack2(o[4], o[5]), pack2(o[6], o[7]) };
        ((uint4*)outp)[(long)node * L + lane] = pv;
    } else {
        float4* op = (float4*)((float*)outp + (long)node * F + c0);
        op[0] = make_float4(o[0], o[1], o[2], o[3]);
        op[1] = make_float4(o[4], o[5], o[6], o[7]);
    }
}

extern "C" void kernel_launch(void* const* d_in, const int* in_sizes, int n_in,
                              void* d_out, int out_size, void* d_ws, size_t ws_size,
                              hipStream_t stream) {
    const void* x  = d_in[0];
    const int*  ei = (const int*)d_in[1];
    const void* W1 = d_in[2];
    const void* b1 = d_in[3];
    const void* W2 = d_in[4];
    const void* b2 = d_in[5];

    const int N = in_sizes[0] / FIN;   // 50000
    const int E = in_sizes[1] / 2;     // 800000
    const int nbuk = (N + NPB - 1) / NPB;   // 511 (<=512 for u16 path)

    // ws layout (bytes), peak ~37.3MB:
    //   flags @0; gcur @4096 (512+2 ints)
    //   cnt @65536 (4N); dinv @266240 (4N)
    //   ovfA @524288; ovf2 @1048576
    //   slots @2097152 (u16 4.8MB / int 9.6MB)
    //   g @11730944 (12.8MB, 2 planes of N*64; g2 overlays)
    //   pairs @24530944 (6.28MB; h1 overlays after binB)
    char* ws = (char*)d_ws;
    int*   flags   = (int*)ws;
    int*   gcur    = (int*)(ws + 4096);
    int*   ovfAcnt = gcur + 512;
    int*   ovf2cnt = gcur + 513;
    int*   cnt     = (int*)(ws + 65536);
    float* dinv    = (float*)(ws + 266240);
    int2*  ovfA    = (int2*)(ws + 524288);
    int2*  ovf2    = (int2*)(ws + 1048576);
    unsigned short* slots16 = (unsigned short*)(ws + 2097152);
    int*   slots32 = (int*)(ws + 2097152);
    __hip_bfloat16* g  = (__hip_bfloat16*)(ws + 11730944);
    __hip_bfloat16* g2 = g;
    unsigned* pairs = (unsigned*)(ws + 24530944);
    __hip_bfloat16* h1 = (__hip_bfloat16*)(ws + 24530944);

    const int GB = (N + 63) / 64;
    const int AB = (E + 2047) / 2048;
    const int EB = (E + 255) / 256;

    if (N <= 65536 && nbuk <= 512) {
        k_detect<<<1, 256, 0, stream>>>((const unsigned*)x, ei, E, flags, gcur, cnt, N, 0);
        k_mega<<<GB + AB, 256, 34816, stream>>>(x, W1, ei, E, N, nbuk, GB,
                                                gcur, pairs, ovfA, ovfAcnt, g, flags);
        k_binB<<<nbuk, 256, 0, stream>>>(gcur, pairs, ovfA, ovfAcnt, cnt, dinv, slots16, ovf2, ovf2cnt, N);
        const int GBL = (N + 31) / 32;
        k_gather1b<<<GBL, 256, 0, stream>>>(g, cnt, dinv, slots16, ovf2, ovf2cnt, b1, h1, flags, N);
        k_gemm<4, 0><<<GB, 256, 0, stream>>>(h1, 0, W2, cnt, g2, flags, N);
        k_gather<64, 0, unsigned short><<<(N + 31) / 32, 256, 0, stream>>>(
            g2, cnt, slots16, ovf2, ovf2cnt, b2, d_out, flags, N);
    } else {
        k_detect<<<64, 256, 0, stream>>>((const unsigned*)x, ei, E, flags, gcur, cnt, N, 1);
        k_build_direct<<<EB, 256, 0, stream>>>(ei, E, N, cnt, slots32, ovf2, ovf2cnt, flags);
        k_gemm<8, 0><<<GB, 256, 0, stream>>>(x, 1, W1, cnt, g, flags, N);
        k_gather<128, 1, int><<<(N + 15) / 16, 256, 0, stream>>>(
            g, cnt, slots32, ovf2, ovf2cnt, b1, h1, flags, N);
        k_gemm<4, 0><<<GB, 256, 0, stream>>>(h1, 0, W2, cnt, g2, flags, N);
        k_gather<64, 0, int><<<(N + 31) / 32, 256, 0, stream>>>(
            g2, cnt, slots32, ovf2, ovf2cnt, b2, d_out, flags, N);
    }
}